// Round 1
// baseline (59.175 us; speedup 1.0000x reference)
//
#include <hip/hip_runtime.h>
#include <hip/hip_bf16.h>

#define B_    32
#define H_IN  80
#define T_IN  1600
#define C1_   32
#define C2_   32
#define H1_   40
#define T1_   800
#define H2_   20
#define T2_   400

typedef __attribute__((ext_vector_type(8))) short short8;
typedef __attribute__((ext_vector_type(4))) float f32x4;

__device__ __forceinline__ unsigned short f2bf(float x) {
    __hip_bfloat16 h = __float2bfloat16(x);
    return __builtin_bit_cast(unsigned short, h);
}

// LDS x1 tile: 9 rows (h1r) x 129 cols (t1r) x 32ch bf16.
// Parity-split on t1r (so B-frag reads walk idx stride-1) + XOR swizzle of the
// 16B channel-chunk slot by (idx&3) -> bank-conflict-free reads AND writes.
__device__ __forceinline__ int x1off(int h1r, int t1r, int g) {
    int idx = t1r >> 1;
    int par = t1r & 1;
    return ((par * (9 * 65) + h1r * 65 + idx) << 6) + (((g ^ idx) & 3) << 4);
}

__global__ __launch_bounds__(256, 2) void fused_conv(
    const float* __restrict__ in, const int* __restrict__ seq,
    const float* __restrict__ W1, const float* __restrict__ b1,
    const float* __restrict__ W2, const float* __restrict__ b2,
    float* __restrict__ out)
{
    __shared__ __align__(16) char smem[2 * 9 * 65 * 64];   // 74880 B

    const int tid  = threadIdx.x;
    const int lane = tid & 63;
    const int wv   = tid >> 6;     // wave id 0..3
    const int l15  = lane & 15;
    const int lg   = lane >> 4;
    const int b      = blockIdx.z;
    const int h2base = blockIdx.y * 4;
    const int t2base = blockIdx.x * 64;
    const int h1base = 2 * h2base - 1;
    const int t1base = 2 * t2base - 1;

    const int L  = seq[b];
    const int L1 = ((L  - 1) >> 1) + 1;
    const int L2 = ((L1 - 1) >> 1) + 1;

    // ---- stage: conv1 + mask + relu -> bf16 LDS tile.  wave wv owns channel chunk wv*8..+7 ----
    float w1r[8][9];
    float b1r[8];
#pragma unroll
    for (int c = 0; c < 8; ++c) {
        b1r[c] = b1[wv * 8 + c];
#pragma unroll
        for (int tap = 0; tap < 9; ++tap)
            w1r[c][tap] = W1[(wv * 8 + c) * 9 + tap];
    }

    const float* inb = in + b * (H_IN * T_IN);
    for (int p = lane; p < 9 * 129; p += 64) {
        int h1r = p / 129;
        int t1r = p - h1r * 129;
        int h1 = h1base + h1r;
        int t1 = t1base + t1r;
        float acc[8];
        bool valid = (h1 >= 0) && (h1 < H1_) && (t1 >= 0) && (t1 < T1_) && (t1 < L1);
        if (valid) {
#pragma unroll
            for (int c = 0; c < 8; ++c) acc[c] = b1r[c];
#pragma unroll
            for (int kh = 0; kh < 3; ++kh) {
                int h = 2 * h1 - 1 + kh;
                bool hok = (h >= 0) && (h < H_IN);
#pragma unroll
                for (int kt = 0; kt < 3; ++kt) {
                    int t = 2 * t1 - 1 + kt;
                    float v = (hok && t >= 0 && t < T_IN) ? inb[h * T_IN + t] : 0.0f;
#pragma unroll
                    for (int c = 0; c < 8; ++c)
                        acc[c] += w1r[c][kh * 3 + kt] * v;
                }
            }
#pragma unroll
            for (int c = 0; c < 8; ++c) acc[c] = fmaxf(acc[c], 0.0f);
        } else {
#pragma unroll
            for (int c = 0; c < 8; ++c) acc[c] = 0.0f;
        }
        short8 xv;
#pragma unroll
        for (int c = 0; c < 8; ++c) xv[c] = (short)f2bf(acc[c]);
        *(short8*)(smem + x1off(h1r, t1r, wv)) = xv;
    }

    __syncthreads();

    // ---- gather conv2 A-fragments (after barrier to keep stage/conv2 VGPR peaks separate) ----
    // A-frag layout (16x16x32): m = lane&15 (c2 within mtile), k = (lane>>4)*8 + j (c1 within tap)
    short8 afr[9][2];
#pragma unroll
    for (int mt = 0; mt < 2; ++mt) {
#pragma unroll
        for (int tap = 0; tap < 9; ++tap) {
            short8 f;
#pragma unroll
            for (int j = 0; j < 8; ++j) {
                int c2 = mt * 16 + l15;
                int c1 = lg * 8 + j;
                f[j] = (short)f2bf(W2[(c2 * 32 + c1) * 9 + tap]);
            }
            afr[tap][mt] = f;
        }
    }
    float b2v[2][4];
#pragma unroll
    for (int mt = 0; mt < 2; ++mt)
#pragma unroll
        for (int j = 0; j < 4; ++j)
            b2v[mt][j] = b2[mt * 16 + lg * 4 + j];

    // ---- conv2: implicit GEMM, wave wv owns t2 strip [t2base+wv*16, +16), 4 h2 rows ----
    f32x4 acc2[2][4];
#pragma unroll
    for (int mt = 0; mt < 2; ++mt)
#pragma unroll
        for (int r = 0; r < 4; ++r)
            acc2[mt][r] = (f32x4){0.f, 0.f, 0.f, 0.f};

#pragma unroll
    for (int tap = 0; tap < 9; ++tap) {
        const int kh = tap / 3;
        const int kt = tap % 3;
        const int t1r = 32 * wv + 2 * l15 + kt;   // = 2*(t2 - t2base) + kt
#pragma unroll
        for (int r = 0; r < 4; ++r) {
            short8 bx = *(const short8*)(smem + x1off(2 * r + kh, t1r, lg));
            acc2[0][r] = __builtin_amdgcn_mfma_f32_16x16x32_bf16(afr[tap][0], bx, acc2[0][r], 0, 0, 0);
            acc2[1][r] = __builtin_amdgcn_mfma_f32_16x16x32_bf16(afr[tap][1], bx, acc2[1][r], 0, 0, 0);
        }
    }

    // ---- epilogue: bias + mask + relu, store fp32 ----
    // D layout (verified m89): col = lane&15 (position), row = (lane>>4)*4 + reg (c2 in mtile)
    const int t2 = t2base + wv * 16 + l15;
    if (t2 < T2_) {
        const bool vmask = (t2 < L2);
#pragma unroll
        for (int mt = 0; mt < 2; ++mt) {
#pragma unroll
            for (int r = 0; r < 4; ++r) {
                int h2 = h2base + r;
#pragma unroll
                for (int j = 0; j < 4; ++j) {
                    int c2 = mt * 16 + lg * 4 + j;
                    float v = acc2[mt][r][j] + b2v[mt][j];
                    v = vmask ? fmaxf(v, 0.0f) : 0.0f;
                    out[((b * C2_ + c2) * H2_ + h2) * T2_ + t2] = v;
                }
            }
        }
    }
}

__global__ void lengths_kernel(const int* __restrict__ seq, float* __restrict__ outL) {
    int i = threadIdx.x;
    if (i < B_) {
        int L  = seq[i];
        int L1 = ((L  - 1) >> 1) + 1;
        int L2 = ((L1 - 1) >> 1) + 1;
        outL[i] = (float)L2;
    }
}

extern "C" void kernel_launch(void* const* d_in, const int* in_sizes, int n_in,
                              void* d_out, int out_size, void* d_ws, size_t ws_size,
                              hipStream_t stream) {
    const float* in  = (const float*)d_in[0];
    const int*   seq = (const int*)d_in[1];
    const float* W1  = (const float*)d_in[2];
    const float* b1  = (const float*)d_in[3];
    const float* W2  = (const float*)d_in[4];
    const float* b2  = (const float*)d_in[5];
    float* out = (float*)d_out;

    dim3 grid(7, 5, 32);   // t2 tiles of 64 (448 padded), h2 tiles of 4, batch
    fused_conv<<<grid, dim3(256), 0, stream>>>(in, seq, W1, b1, W2, b2, out);
    lengths_kernel<<<1, 64, 0, stream>>>(seq, out + (size_t)(B_ * C2_ * H2_ * T2_));
}

// Round 2
// 56.926 us; speedup vs baseline: 1.0395x; 1.0395x over previous
//
#include <hip/hip_runtime.h>
#include <hip/hip_bf16.h>

#define B_    32
#define H_IN  80
#define T_IN  1600
#define C1_   32
#define C2_   32
#define H1_   40
#define T1_   800
#define H2_   20
#define T2_   400

// tile geometry
#define TH2   2            // h2 rows per block
#define TT2   64           // t2 cols per block
#define NH1   5            // 2*TH2+1 conv1 rows needed
#define NT1   129          // 2*TT2+1 conv1 cols needed
#define RROWS 11           // 2*NH1+1 raw input rows
#define RCOLS 260          // >= 2*NT1+1 raw input cols (iterated)
#define RSTR  264          // padded row stride (floats)

typedef __attribute__((ext_vector_type(8))) short short8;
typedef __attribute__((ext_vector_type(4))) float f32x4;
typedef __attribute__((ext_vector_type(2))) float f32x2;

__device__ __forceinline__ unsigned short f2bf(float x) {
    __hip_bfloat16 h = __float2bfloat16(x);
    return __builtin_bit_cast(unsigned short, h);
}

// x1 LDS tile: parity-split on t1r + XOR swizzle of the 16B channel-chunk slot.
__device__ __forceinline__ int x1off(int h1r, int t1r, int g) {
    int idx = t1r >> 1;
    int par = t1r & 1;
    return ((par * (NH1 * 65) + h1r * 65 + idx) << 6) + (((g ^ idx) & 3) << 4);
}

__global__ __launch_bounds__(256, 3) void fused_conv(
    const float* __restrict__ in, const int* __restrict__ seq,
    const float* __restrict__ W1, const float* __restrict__ b1,
    const float* __restrict__ W2, const float* __restrict__ b2,
    float* __restrict__ out)
{
    __shared__ __align__(16) char  x1mem[2 * NH1 * 65 * 64];   // 41600 B
    __shared__ __align__(16) float raw[RROWS][RSTR];           // 11616 B

    const int tid  = threadIdx.x;
    const int lane = tid & 63;
    const int wv   = tid >> 6;
    const int l15  = lane & 15;
    const int lg   = lane >> 4;
    const int b      = blockIdx.z;
    const int h2base = blockIdx.y * TH2;
    const int t2base = blockIdx.x * TT2;

    const int L  = seq[b];
    const int L1 = ((L  - 1) >> 1) + 1;
    const int L2 = ((L1 - 1) >> 1) + 1;

    // ---- early-out: whole t-tile is beyond L2 -> output tile is all zeros ----
    if (t2base >= L2) {
        const int t2 = t2base + lane;
        if (t2 < T2_) {
            for (int combo = wv; combo < C2_ * TH2; combo += 4) {
                int c2 = combo >> 1;
                int r  = combo & 1;
                out[((b * C2_ + c2) * H2_ + h2base + r) * T2_ + t2] = 0.0f;
            }
        }
        return;
    }

    // ---- phase 0: coalesced branch-free stage of raw input tile into LDS ----
    const int row0 = 4 * h2base - 3;
    const int t0   = 4 * t2base - 3;
    const float* inb = in + b * (H_IN * T_IN);
    for (int p = tid; p < RROWS * RCOLS; p += 256) {
        int row = p / RCOLS;
        int col = p - row * RCOLS;
        int h = row0 + row;
        int t = t0 + col;
        bool ok = (h >= 0) & (h < H_IN) & (t >= 0) & (t < T_IN);
        int gidx = ok ? (h * T_IN + t) : 0;
        float v = inb[gidx];
        raw[row][col] = ok ? v : 0.0f;
    }

    // conv1 weights: wave wv owns channels wv*8 .. wv*8+7
    float w1r[8][9];
    float b1r[8];
    const int cb = wv * 8;
#pragma unroll
    for (int c = 0; c < 8; ++c) {
        b1r[c] = b1[cb + c];
#pragma unroll
        for (int tap = 0; tap < 9; ++tap)
            w1r[c][tap] = W1[(cb + c) * 9 + tap];
    }

    __syncthreads();

    // ---- phase 1: conv1 + mask + relu from LDS raw -> bf16 x1 tile in LDS ----
    const int h1base = 2 * h2base - 1;
    const int t1base = 2 * t2base - 1;
    for (int p = lane; p < NH1 * NT1; p += 64) {
        int h1r = p / NT1;
        int t1r = p - h1r * NT1;
        int h1 = h1base + h1r;
        int t1 = t1base + t1r;
        float acc[8];
#pragma unroll
        for (int c = 0; c < 8; ++c) acc[c] = b1r[c];
#pragma unroll
        for (int kh = 0; kh < 3; ++kh) {
            const float* rp = &raw[2 * h1r + kh][2 * t1r];
            f32x2 v01 = *(const f32x2*)rp;
            float v2  = rp[2];
#pragma unroll
            for (int c = 0; c < 8; ++c) {
                acc[c] = fmaf(v01[0], w1r[c][kh * 3 + 0], acc[c]);
                acc[c] = fmaf(v01[1], w1r[c][kh * 3 + 1], acc[c]);
                acc[c] = fmaf(v2,     w1r[c][kh * 3 + 2], acc[c]);
            }
        }
        bool ok = (h1 >= 0) && (t1 >= 0) && (t1 < L1);
        short8 xv;
#pragma unroll
        for (int c = 0; c < 8; ++c) {
            float v = ok ? fmaxf(acc[c], 0.0f) : 0.0f;
            xv[c] = (short)f2bf(v);
        }
        *(short8*)(x1mem + x1off(h1r, t1r, wv)) = xv;
    }

    __syncthreads();

    // ---- conv2 A-fragments: coalesced float4 loads of W2 (72 contiguous floats/lane) ----
    // A-frag (16x16x32): m = lane&15 (c2 in mtile), k = (lane>>4)*8 + j (c1 in tap)
    short8 afr[9][2];
#pragma unroll
    for (int mt = 0; mt < 2; ++mt) {
        int c2 = mt * 16 + l15;
        const f32x4* wp = (const f32x4*)(W2 + c2 * 288 + lg * 72);
        f32x4 wb[18];
#pragma unroll
        for (int q = 0; q < 18; ++q) wb[q] = wp[q];
        const float* wf = (const float*)wb;
#pragma unroll
        for (int tap = 0; tap < 9; ++tap) {
            short8 f;
#pragma unroll
            for (int j = 0; j < 8; ++j)
                f[j] = (short)f2bf(wf[j * 9 + tap]);   // (c1r=j, tap)
            afr[tap][mt] = f;
        }
    }
    float b2v[2][4];
#pragma unroll
    for (int mt = 0; mt < 2; ++mt)
#pragma unroll
        for (int j = 0; j < 4; ++j)
            b2v[mt][j] = b2[mt * 16 + lg * 4 + j];

    // ---- phase 2: conv2 implicit GEMM; wave wv owns t2 strip [t2base+wv*16, +16) ----
    f32x4 acc2[2][TH2];
#pragma unroll
    for (int mt = 0; mt < 2; ++mt)
#pragma unroll
        for (int r = 0; r < TH2; ++r)
            acc2[mt][r] = (f32x4){0.f, 0.f, 0.f, 0.f};

#pragma unroll
    for (int tap = 0; tap < 9; ++tap) {
        const int kh = tap / 3;
        const int kt = tap % 3;
        const int t1r = 2 * (wv * 16 + l15) + kt;
#pragma unroll
        for (int r = 0; r < TH2; ++r) {
            short8 bx = *(const short8*)(x1mem + x1off(2 * r + kh, t1r, lg));
            acc2[0][r] = __builtin_amdgcn_mfma_f32_16x16x32_bf16(afr[tap][0], bx, acc2[0][r], 0, 0, 0);
            acc2[1][r] = __builtin_amdgcn_mfma_f32_16x16x32_bf16(afr[tap][1], bx, acc2[1][r], 0, 0, 0);
        }
    }

    // ---- epilogue: bias + mask + relu, fp32 stores ----
    // D layout: col = lane&15 (t2), row = (lane>>4)*4 + reg (c2 in mtile)
    const int t2 = t2base + wv * 16 + l15;
    if (t2 < T2_) {
        const bool vmask = (t2 < L2);
#pragma unroll
        for (int mt = 0; mt < 2; ++mt) {
#pragma unroll
            for (int r = 0; r < TH2; ++r) {
                int h2 = h2base + r;
#pragma unroll
                for (int j = 0; j < 4; ++j) {
                    int c2 = mt * 16 + lg * 4 + j;
                    float v = acc2[mt][r][j] + b2v[mt][j];
                    v = vmask ? fmaxf(v, 0.0f) : 0.0f;
                    out[((b * C2_ + c2) * H2_ + h2) * T2_ + t2] = v;
                }
            }
        }
    }
}

__global__ void lengths_kernel(const int* __restrict__ seq, float* __restrict__ outL) {
    int i = threadIdx.x;
    if (i < B_) {
        int L  = seq[i];
        int L1 = ((L  - 1) >> 1) + 1;
        int L2 = ((L1 - 1) >> 1) + 1;
        outL[i] = (float)L2;
    }
}

extern "C" void kernel_launch(void* const* d_in, const int* in_sizes, int n_in,
                              void* d_out, int out_size, void* d_ws, size_t ws_size,
                              hipStream_t stream) {
    const float* in  = (const float*)d_in[0];
    const int*   seq = (const int*)d_in[1];
    const float* W1  = (const float*)d_in[2];
    const float* b1  = (const float*)d_in[3];
    const float* W2  = (const float*)d_in[4];
    const float* b2  = (const float*)d_in[5];
    float* out = (float*)d_out;

    dim3 grid(7, 10, 32);   // t2 tiles of 64, h2 tiles of 2, batch
    fused_conv<<<grid, dim3(256), 0, stream>>>(in, seq, W1, b1, W2, b2, out);
    lengths_kernel<<<1, 64, 0, stream>>>(seq, out + (size_t)(B_ * C2_ * H2_ * T2_));
}

// Round 3
// 39.691 us; speedup vs baseline: 1.4909x; 1.4342x over previous
//
#include <hip/hip_runtime.h>
#include <hip/hip_bf16.h>

#define B_    32
#define H_IN  80
#define T_IN  1600
#define C1_   32
#define H1_   40
#define T1_   800
#define C2_   32
#define H2_   20
#define T2_   400

// tile geometry
#define TH2   2            // h2 rows per block
#define TT2   32           // t2 cols per block
#define NH1   5            // 2*TH2+1 conv1 rows
#define NT1   65           // 2*TT2+1 conv1 cols
#define NIDX  33           // ceil(NT1/2)
#define RROWS 11           // raw input rows
#define RCOLS 131          // raw input cols
#define RSTR  132          // padded row stride

#define NPOS  (NH1 * NT1)       // 325 conv1 positions
#define RTOT  (RROWS * RCOLS)   // 1441 raw elements
#define WSFRAGS 1152            // 2 mt * 9 tap * 64 lane
#define WSBYTES (WSFRAGS * 16)  // 18432

typedef __attribute__((ext_vector_type(8))) short short8;
typedef __attribute__((ext_vector_type(4))) float f32x4;
typedef __attribute__((ext_vector_type(2))) float f32x2;

__device__ __forceinline__ unsigned short f2bf(float x) {
    __hip_bfloat16 h = __float2bfloat16(x);
    return __builtin_bit_cast(unsigned short, h);
}
__device__ __forceinline__ float rfl(float x) {
    return __builtin_bit_cast(float,
        __builtin_amdgcn_readfirstlane(__builtin_bit_cast(int, x)));
}

// x1 LDS tile: parity-split on t1r + XOR swizzle of the 16B channel-chunk slot.
__device__ __forceinline__ int x1off(int h1r, int t1r, int g) {
    int idx = t1r >> 1;
    int par = t1r & 1;
    return ((par * (NH1 * NIDX) + h1r * NIDX + idx) << 6) + (((g ^ idx) & 3) << 4);
}

// ---- prep: repack W2 into MFMA A-fragment bf16 layout in d_ws ----
// item i = mt*576 + tap*64 + lane (lane = lg*16+l15); frag[j] = W2[c2=mt*16+l15][c1=lg*8+j][tap]
__global__ void w2prep(const float* __restrict__ W2, unsigned short* __restrict__ ws) {
    int i = blockIdx.x * 256 + threadIdx.x;
    if (i < WSFRAGS) {
        int mt   = i / 576;
        int rem  = i - mt * 576;
        int tap  = rem >> 6;
        int lane = rem & 63;
        int lg   = lane >> 4;
        int l15  = lane & 15;
        int c2   = mt * 16 + l15;
        short8 f;
#pragma unroll
        for (int j = 0; j < 8; ++j)
            f[j] = (short)f2bf(W2[((c2 * C1_) + lg * 8 + j) * 9 + tap]);
        *((short8*)ws + i) = f;
    }
}

__global__ __launch_bounds__(256, 6) void fused_conv(
    const float* __restrict__ in, const int* __restrict__ seq,
    const float* __restrict__ W1, const float* __restrict__ b1,
    const float* __restrict__ W2, const float* __restrict__ b2,
    const unsigned short* __restrict__ ws, int use_ws,
    float* __restrict__ out)
{
    __shared__ __align__(16) char  x1mem[2 * NH1 * NIDX * 64];  // 21120 B (reused as obuf)
    __shared__ __align__(16) float raw[RROWS][RSTR];            // 5808 B

    const int tid  = threadIdx.x;
    const int lane = tid & 63;
    const int wv   = tid >> 6;
    const int l15  = lane & 15;
    const int lg   = lane >> 4;
    const int b      = blockIdx.z;
    const int h2base = blockIdx.y * TH2;
    const int t2base = blockIdx.x * TT2;

    const int L  = seq[b];
    const int L1 = ((L  - 1) >> 1) + 1;
    const int L2 = ((L1 - 1) >> 1) + 1;

    // ---- early-out: whole t-tile beyond L2 -> zeros, full-line stores ----
    if (t2base >= L2) {
#pragma unroll
        for (int k = 0; k < 8; ++k) {
            int i = tid + k * 256;                  // 64 rows x 32 cols
            int row = i >> 5, col = i & 31;
            int c2 = row >> 1, r = row & 1;
            int t2 = t2base + col;
            if (t2 < T2_)
                out[((b * C2_ + c2) * H2_ + h2base + r) * T2_ + t2] = 0.0f;
        }
        return;
    }

    // ---- phase 0: coalesced branch-free stage of raw input tile ----
    const int row0 = 4 * h2base - 3;
    const int t0   = 4 * t2base - 3;
    const float* inb = in + b * (H_IN * T_IN);
#pragma unroll
    for (int k = 0; k < 6; ++k) {
        int idx = tid + k * 256;
        if (idx < RTOT) {
            int row = idx / RCOLS;
            int col = idx - row * RCOLS;
            int h = row0 + row;
            int t = t0 + col;
            bool ok = (h >= 0) & (h < H_IN) & (t >= 0) & (t < T_IN);
            float v = inb[ok ? h * T_IN + t : 0];
            raw[row][col] = ok ? v : 0.0f;
        }
    }

    // conv1 weights -> SGPRs (wave-uniform): wave wv owns channels wv*8..+7
    float w1s[8][9], b1s[8];
    const int cb = wv * 8;
#pragma unroll
    for (int c = 0; c < 8; ++c) {
        b1s[c] = rfl(b1[cb + c]);
#pragma unroll
        for (int tap = 0; tap < 9; ++tap)
            w1s[c][tap] = rfl(W1[(cb + c) * 9 + tap]);
    }

    __syncthreads();

    // ---- phase 1: conv1 + mask + relu -> bf16 x1 tile ----
    const int h1base = 2 * h2base - 1;
    const int t1base = 2 * t2base - 1;
#pragma unroll
    for (int k = 0; k < 6; ++k) {
        int p = lane + k * 64;
        if (p < NPOS) {
            int h1r = p / NT1;
            int t1r = p - h1r * NT1;
            int h1 = h1base + h1r;
            int t1 = t1base + t1r;
            float acc[8];
#pragma unroll
            for (int c = 0; c < 8; ++c) acc[c] = b1s[c];
#pragma unroll
            for (int kh = 0; kh < 3; ++kh) {
                const float* rp = &raw[2 * h1r + kh][2 * t1r];
                f32x2 v01 = *(const f32x2*)rp;
                float v2  = rp[2];
#pragma unroll
                for (int c = 0; c < 8; ++c) {
                    acc[c] = fmaf(v01[0], w1s[c][kh * 3 + 0], acc[c]);
                    acc[c] = fmaf(v01[1], w1s[c][kh * 3 + 1], acc[c]);
                    acc[c] = fmaf(v2,     w1s[c][kh * 3 + 2], acc[c]);
                }
            }
            bool ok = (h1 >= 0) && (t1 >= 0) && (t1 < L1);
            short8 xv;
#pragma unroll
            for (int c = 0; c < 8; ++c) {
                float v = ok ? fmaxf(acc[c], 0.0f) : 0.0f;
                xv[c] = (short)f2bf(v);
            }
            *(short8*)(x1mem + x1off(h1r, t1r, wv)) = xv;
        }
    }

    __syncthreads();

    // ---- phase 2: conv2 implicit GEMM. wave = (strip, mt); rows r=0..1 internal ----
    const int strip = wv >> 1;
    const int mt    = wv & 1;

    short8 afr[9];
    if (use_ws) {
#pragma unroll
        for (int tap = 0; tap < 9; ++tap)
            afr[tap] = *((const short8*)ws + (mt * 9 + tap) * 64 + lane);
    } else {
        const int c2 = mt * 16 + l15;
#pragma unroll
        for (int tap = 0; tap < 9; ++tap) {
            short8 f;
#pragma unroll
            for (int j = 0; j < 8; ++j)
                f[j] = (short)f2bf(W2[(c2 * C1_ + lg * 8 + j) * 9 + tap]);
            afr[tap] = f;
        }
    }
    float b2r[4];
#pragma unroll
    for (int j = 0; j < 4; ++j) b2r[j] = b2[mt * 16 + lg * 4 + j];

    f32x4 acc2[TH2];
#pragma unroll
    for (int r = 0; r < TH2; ++r) acc2[r] = (f32x4){0.f, 0.f, 0.f, 0.f};

#pragma unroll
    for (int tap = 0; tap < 9; ++tap) {
        const int kh = tap / 3;
        const int kt = tap % 3;
        const int t1r = 2 * (strip * 16 + l15) + kt;
#pragma unroll
        for (int r = 0; r < TH2; ++r) {
            short8 bx = *(const short8*)(x1mem + x1off(2 * r + kh, t1r, lg));
            acc2[r] = __builtin_amdgcn_mfma_f32_16x16x32_bf16(afr[tap], bx, acc2[r], 0, 0, 0);
        }
    }

    __syncthreads();   // x1 reads done; reuse x1mem as obuf [64 rows][33]

    // D layout: col(l15)=t2 within strip, row=(lg*4+j)=c2 within mtile
    float* obuf = (float*)x1mem;
    {
        const int t2 = t2base + strip * 16 + l15;
        const bool vm = (t2 < L2);
#pragma unroll
        for (int r = 0; r < TH2; ++r) {
#pragma unroll
            for (int j = 0; j < 4; ++j) {
                int c2 = mt * 16 + lg * 4 + j;
                float v = acc2[r][j] + b2r[j];
                v = vm ? fmaxf(v, 0.0f) : 0.0f;
                obuf[(c2 * TH2 + r) * 33 + strip * 16 + l15] = v;
            }
        }
    }
    __syncthreads();

    // ---- coalesced fp32 stores: 128B segments ----
#pragma unroll
    for (int k = 0; k < 8; ++k) {
        int i = tid + k * 256;                  // 64 rows x 32 cols
        int row = i >> 5, col = i & 31;
        int c2 = row >> 1, r = row & 1;
        int t2 = t2base + col;
        if (t2 < T2_)
            out[((b * C2_ + c2) * H2_ + h2base + r) * T2_ + t2] = obuf[row * 33 + col];
    }
}

__global__ void lengths_kernel(const int* __restrict__ seq, float* __restrict__ outL) {
    int i = threadIdx.x;
    if (i < B_) {
        int L  = seq[i];
        int L1 = ((L  - 1) >> 1) + 1;
        int L2 = ((L1 - 1) >> 1) + 1;
        outL[i] = (float)L2;
    }
}

extern "C" void kernel_launch(void* const* d_in, const int* in_sizes, int n_in,
                              void* d_out, int out_size, void* d_ws, size_t ws_size,
                              hipStream_t stream) {
    const float* in  = (const float*)d_in[0];
    const int*   seq = (const int*)d_in[1];
    const float* W1  = (const float*)d_in[2];
    const float* b1  = (const float*)d_in[3];
    const float* W2  = (const float*)d_in[4];
    const float* b2  = (const float*)d_in[5];
    float* out = (float*)d_out;

    const int use_ws = (ws_size >= (size_t)WSBYTES) ? 1 : 0;
    unsigned short* ws = (unsigned short*)d_ws;

    if (use_ws)
        w2prep<<<dim3((WSFRAGS + 255) / 256), dim3(256), 0, stream>>>(W2, ws);

    dim3 grid((T2_ + TT2 - 1) / TT2, H2_ / TH2, B_);   // 13 x 10 x 32
    fused_conv<<<grid, dim3(256), 0, stream>>>(in, seq, W1, b1, W2, b2, ws, use_ws, out);
    lengths_kernel<<<1, 64, 0, stream>>>(seq, out + (size_t)(B_ * C2_ * H2_ * T2_));
}